// Round 9
// baseline (42.993 us; speedup 1.0000x reference)
//
#include <hip/hip_runtime.h>
#include <hip/hip_bf16.h>

// out[b,o] = sum_{i,n} T_n(x[b,i]) * w[o,i,n]
// GEMM view: M=B=65536, N=O=32, K=I*8=2048. MFMA v_mfma_f32_32x32x16_bf16.
// Round-9: persistent blocks + wave-level software pipeline.
//   512 blocks (2/CU), 4 tiles each (stride 512), 64 KB double-buffered LDS.
//   Per tile: issue NEXT tile's global loads -> compute current tile ->
//   partials -> reduce/store -> ds_write landed loads into other buffer.
//   Loads are in flight during the whole compute => continuous memory demand,
//   no stage/compute burst alternation (the ~31 us plateau's cause).
//   B-fragments live in registers for the whole block (ball[32], loaded once).
//   Inner loop + all layouts byte-identical to proven rounds 6/8.

typedef __attribute__((ext_vector_type(8)))  short bf16x8;
typedef __attribute__((ext_vector_type(16))) float f32x16;
typedef __attribute__((ext_vector_type(4)))  float f32x4;

__device__ __forceinline__ short f2b(float f) {
    __hip_bfloat16 h = __float2bfloat16(f);
    short s;
    __builtin_memcpy(&s, &h, sizeof(s));
    return s;
}

__device__ __forceinline__ unsigned pkbf(float lo, float hi) {
    __hip_bfloat162 h2 = __float22bfloat162_rn(make_float2(lo, hi));
    unsigned u;
    __builtin_memcpy(&u, &h2, 4);
    return u;
}

// Pack w [32][256][8] fp32 -> wB[kc2][lane][jj] bf16 in B-fragment order:
//   o = lane&31, g = lane>>5, i = 2*kc2 + (jj>>2), n = 4*g + (jj&3)
// (HW-verified: rounds 2-8 passed with this layout, absmax 1.95e-3)
__global__ __launch_bounds__(256) void prep_w_kernel(const float* __restrict__ w,
                                                     short* __restrict__ wB) {
    int idx = blockIdx.x * 256 + threadIdx.x;     // 0..65535
    int kc2 = idx >> 9;
    int l   = (idx >> 3) & 63;
    int jj  = idx & 7;
    int o = l & 31, g = l >> 5;
    int i = 2 * kc2 + (jj >> 2);
    int n = 4 * g + (jj & 3);
    wB[idx] = f2b(w[(o * 256 + i) * 8 + n]);
}

__global__ __launch_bounds__(256, 2) void cheb_mm_kernel(const float* __restrict__ x,
                                                         const short* __restrict__ wB,
                                                         float* __restrict__ out) {
    __shared__ float smem[16384];                 // 64 KB = 2 x 32 KB buffers
    const int tid = threadIdx.x;
    const int wv  = tid >> 6;                     // K-quarter / column-slice
    const int l   = tid & 63;
    const int g   = l >> 5;                       // i-parity this lane computes
    const int r0  = l & 31;                       // batch row in tile / o column
    const int f4l = l & 15;                       // 16 float4 per row-slice
    const int rsub = l >> 4;                      // 4 rows per pass

    float4 stg[8];                                // in-flight next-tile slice

    // tile T's x: rows [T*32, T*32+32), this wave's float cols [wv*64,+64)
    auto LOADT = [&](int T) {
        const float4* xg4 = (const float4*)x + (long long)T * 2048;
        #pragma unroll
        for (int q = 0; q < 8; ++q)
            stg[q] = xg4[(q * 4 + rsub) * 64 + wv * 16 + f4l];
    };
    auto WRITET = [&](int buf) {                  // proven XOR swizzle (r8)
        #pragma unroll
        for (int q = 0; q < 8; ++q) {
            const int row  = q * 4 + rsub;
            const int base = buf * 8192 + row * 256 + wv * 64;
            const int s    = row & 31;
            const int p0 = 2 * f4l, p1 = 2 * f4l + 1;
            *(float2*)&smem[base + 2 * (p0 ^ s)] = make_float2(stg[q].x, stg[q].y);
            *(float2*)&smem[base + 2 * (p1 ^ s)] = make_float2(stg[q].z, stg[q].w);
        }
    };

    const int T0 = blockIdx.x;                    // tiles T0 + 512*tt, tt=0..3

    LOADT(T0);                                    // longest-latency first

    // B-fragments for this wave's K-quarter: registers for the whole block.
    // Full unroll => static indices (stays in VGPRs, no scratch).
    const bf16x8* wq = (const bf16x8*)wB + wv * 2048 + l;
    bf16x8 ball[32];
    #pragma unroll
    for (int t = 0; t < 32; ++t) ball[t] = wq[t * 64];

    WRITET(0);                                    // drains stg (ball lands too)

    for (int tt = 0; tt < 4; ++tt) {
        const int p = tt & 1;
        const long long rowB = (long long)(T0 + 512 * tt) * 32;

        if (tt < 3) LOADT(T0 + 512 * (tt + 1));   // fly under compute

        // ---- compute tile tt from buf p (round-6/8 proven body) ----
        f32x16 accA{}, accB{};
        const float* sf = smem + p * 8192;
        const int xbase = r0 * 256 + wv * 64 + g;
        float xc[2];
        xc[0] = sf[xbase + ((0 ^ r0) << 1)];
        xc[1] = sf[xbase + ((1 ^ r0) << 1)];

        #pragma unroll
        for (int t = 0; t < 32; ++t) {
            const bf16x8 bfrag = ball[t];
            const float  xv    = xc[t & 1];
            if (t + 2 < 32) xc[t & 1] = sf[xbase + (((t + 2) ^ r0) << 1)];

            const float x2 = xv + xv;
            const float T2 = fmaf(x2, xv, -1.f);
            const float T3 = fmaf(x2, T2, -xv);
            const float T4 = fmaf(x2, T3, -T2);
            const float T5 = fmaf(x2, T4, -T3);
            const float T6 = fmaf(x2, T5, -T4);
            const float T7 = fmaf(x2, T6, -T5);
            unsigned R0 = pkbf(1.f, xv);
            unsigned R1 = pkbf(T2, T3);
            unsigned R2 = pkbf(T4, T5);
            unsigned R3 = pkbf(T6, T7);
            auto r02 = __builtin_amdgcn_permlane32_swap(R0, R2, false, false);
            auto r13 = __builtin_amdgcn_permlane32_swap(R1, R3, false, false);
            union { unsigned u[4]; bf16x8 v; } af;
            af.u[0] = r02[0]; af.u[1] = r13[0];
            af.u[2] = r02[1]; af.u[3] = r13[1];
            if (t & 1)
                accB = __builtin_amdgcn_mfma_f32_32x32x16_bf16(af.v, bfrag, accB, 0, 0, 0);
            else
                accA = __builtin_amdgcn_mfma_f32_32x32x16_bf16(af.v, bfrag, accA, 0, 0, 0);
        }
        const f32x16 acc = accA + accB;

        // partials into this wave's own (now dead) slice of buf p
        #pragma unroll
        for (int r = 0; r < 16; ++r) {
            const int rloc = (r & 3) + 8 * (r >> 2) + 4 * g;   // C/D row (HW-ok)
            smem[p * 8192 + rloc * 256 + wv * 64 + r0] = acc[r];
        }
        __syncthreads();                          // partials visible to all

        // cross-wave reduce + coalesced f32x4 store of out tile
        {
            float* op = out + rowB * 32;
            const int f   = tid * 4;
            const int row = f >> 5;
            const int c   = f & 31;
            const int b   = p * 8192 + row * 256 + c;
            f32x4 v0 = *(const f32x4*)&smem[b];
            f32x4 v1 = *(const f32x4*)&smem[b + 64];
            f32x4 v2 = *(const f32x4*)&smem[b + 128];
            f32x4 v3 = *(const f32x4*)&smem[b + 192];
            f32x4 s = (v0 + v1) + (v2 + v3);
            *(f32x4*)(op + f) = s;
        }
        __syncthreads();                          // reduce done before re-write

        if (tt < 3) WRITET(p ^ 1);                // land prefetched tile
    }
}

extern "C" void kernel_launch(void* const* d_in, const int* in_sizes, int n_in,
                              void* d_out, int out_size, void* d_ws, size_t ws_size,
                              hipStream_t stream) {
    const float* x = (const float*)d_in[0];   // [65536, 256] fp32
    const float* w = (const float*)d_in[1];   // [32, 256, 8] fp32
    float* out = (float*)d_out;               // [65536, 32] fp32
    short* wB = (short*)d_ws;                 // 128 KB bf16 packed weights

    prep_w_kernel<<<256, 256, 0, stream>>>(w, wB);
    cheb_mm_kernel<<<512, 256, 0, stream>>>(x, wB, out);
}

// Round 10
// 29.097 us; speedup vs baseline: 1.4776x; 1.4776x over previous
//
#include <hip/hip_runtime.h>
#include <hip/hip_bf16.h>

// out[b,o] = sum_{i,n} T_n(x[b,i]) * w[o,i,n]
// GEMM view: M=B=65536, N=O=32, K=I*8=2048. MFMA v_mfma_f32_32x32x16_bf16.
// Round-10 = Round-8 structure (PASSED, 31.05 us: wave-private barrier-free
// staging, 2048 blocks, 32KB LDS, bfc[4]) with a slimmed inner body:
//  - bf16 A-pack via single v_perm_b32 TRUNCATION (was lib RN pack, the
//    suspected multi-instr hot spot; w stays RN in prep so only A truncates)
//  - LDS addr via base0 ^ (2t) const-XOR (bits disjoint, 1 VALU/iter)
//  - xc prefetch depth 4 (covers ~120cy ds_read latency)

typedef __attribute__((ext_vector_type(8)))  short bf16x8;
typedef __attribute__((ext_vector_type(16))) float f32x16;
typedef __attribute__((ext_vector_type(4)))  float f32x4;

__device__ __forceinline__ short f2b(float f) {     // RN (prep only)
    __hip_bfloat16 h = __float2bfloat16(f);
    short s;
    __builtin_memcpy(&s, &h, sizeof(s));
    return s;
}

// pack {hi16(hi), hi16(lo)} in ONE v_perm_b32 (truncating bf16 pack)
__device__ __forceinline__ unsigned pkbf_tr(float lo, float hi) {
    unsigned a, b;
    __builtin_memcpy(&a, &hi, 4);
    __builtin_memcpy(&b, &lo, 4);
    return __builtin_amdgcn_perm(a, b, 0x07060302u);
}

// Pack w [32][256][8] fp32 -> wB[kc2][lane][jj] bf16 in B-fragment order:
//   o = lane&31, g = lane>>5, i = 2*kc2 + (jj>>2), n = 4*g + (jj&3)
// (HW-verified: rounds 2-9 passed with this layout)
__global__ __launch_bounds__(256) void prep_w_kernel(const float* __restrict__ w,
                                                     short* __restrict__ wB) {
    int idx = blockIdx.x * 256 + threadIdx.x;     // 0..65535
    int kc2 = idx >> 9;
    int l   = (idx >> 3) & 63;
    int jj  = idx & 7;
    int o = l & 31, g = l >> 5;
    int i = 2 * kc2 + (jj >> 2);
    int n = 4 * g + (jj & 3);
    wB[idx] = f2b(w[(o * 256 + i) * 8 + n]);
}

__global__ __launch_bounds__(256, 5) void cheb_mm_kernel(const float* __restrict__ x,
                                                         const short* __restrict__ wB,
                                                         float* __restrict__ out) {
    __shared__ float smem[8192];                  // 32 KB: x tile, then partials
    const int tid = threadIdx.x;
    const int wv  = tid >> 6;                     // K-quarter / column-slice
    const int l   = tid & 63;
    const int g   = l >> 5;                       // i-parity this lane computes
    const int r0  = l & 31;                       // batch row in tile / o column
    const long long rowB = (long long)blockIdx.x * 32;

    const bf16x8* wq = (const bf16x8*)wB + wv * 2048 + l;
    // early B prefetch: issue before staging so it flies under the x wait
    bf16x8 bfc[4];
    #pragma unroll
    for (int p = 0; p < 4; ++p) bfc[p] = wq[p * 64];

    // ---- wave-private stage: rows 0..31, float cols [wv*64, wv*64+64) ----
    // NO barrier: this wave is the only reader of this slice. (R8-proven)
    {
        const float4* xg4 = (const float4*)(x + rowB * 256);
        const int f4l = l & 15;                   // 16 float4 per row-slice
        const int rsub = l >> 4;                  // 4 rows per pass
        float4 stg[8];
        #pragma unroll
        for (int q = 0; q < 8; ++q)
            stg[q] = xg4[(q * 4 + rsub) * 64 + wv * 16 + f4l];   // all in flight
        #pragma unroll
        for (int q = 0; q < 8; ++q) {
            const int row  = q * 4 + rsub;
            const int base = row * 256 + wv * 64; // dword base of slice row
            const int s    = row & 31;
            const int p0 = 2 * f4l, p1 = 2 * f4l + 1;   // local f2 idx 0..31
            *(float2*)&smem[base + 2 * (p0 ^ s)] = make_float2(stg[q].x, stg[q].y);
            *(float2*)&smem[base + 2 * (p1 ^ s)] = make_float2(stg[q].z, stg[q].w);
        }
    }

    // ---- compute: kc2 = wv*32+t, t=0..31 ----
    f32x16 accA{}, accB{};
    const float* sf = smem;
    // base0: xbase | (r0<<1); swizzled idx_t = base0 ^ (2t)  (bits disjoint)
    const int base0 = r0 * 256 + wv * 64 + g + (r0 << 1);

    float xc[4];
    #pragma unroll
    for (int i0 = 0; i0 < 4; ++i0) xc[i0] = sf[base0 ^ (i0 << 1)];

    #pragma unroll
    for (int t = 0; t < 32; ++t) {
        const bf16x8 bfrag = bfc[t & 3];
        const float  xv    = xc[t & 3];
        if (t + 4 < 32) {
            bfc[t & 3] = wq[(t + 4) * 64];
            xc[t & 3]  = sf[base0 ^ ((t + 4) << 1)];
        }

        const float x2 = xv + xv;
        const float T2 = fmaf(x2, xv, -1.f);
        const float T3 = fmaf(x2, T2, -xv);
        const float T4 = fmaf(x2, T3, -T2);
        const float T5 = fmaf(x2, T4, -T3);
        const float T6 = fmaf(x2, T5, -T4);
        const float T7 = fmaf(x2, T6, -T5);
        unsigned R0 = pkbf_tr(1.f, xv);           // 1 v_perm_b32 each
        unsigned R1 = pkbf_tr(T2, T3);
        unsigned R2 = pkbf_tr(T4, T5);
        unsigned R3 = pkbf_tr(T6, T7);
        // hazard-safe builtin; rounds 6/8 HW-verified wiring
        auto r02 = __builtin_amdgcn_permlane32_swap(R0, R2, false, false);
        auto r13 = __builtin_amdgcn_permlane32_swap(R1, R3, false, false);
        union { unsigned u[4]; bf16x8 v; } af;
        af.u[0] = r02[0]; af.u[1] = r13[0];
        af.u[2] = r02[1]; af.u[3] = r13[1];
        if (t & 1)
            accB = __builtin_amdgcn_mfma_f32_32x32x16_bf16(af.v, bfrag, accB, 0, 0, 0);
        else
            accA = __builtin_amdgcn_mfma_f32_32x32x16_bf16(af.v, bfrag, accA, 0, 0, 0);
    }
    const f32x16 acc = accA + accB;

    // ---- partials into this wave's own (dead) slice: no barrier needed ----
    #pragma unroll
    for (int r = 0; r < 16; ++r) {
        const int rloc = (r & 3) + 8 * (r >> 2) + 4 * g;   // C/D row (HW-verified)
        smem[rloc * 256 + wv * 64 + r0] = acc[r];
    }
    __syncthreads();                              // the block's ONLY barrier

    // ---- cross-wave reduce + coalesced f32x4 store of out[32][32] ----
    {
        float* op = out + rowB * 32;
        const int f   = tid * 4;                  // 1024 floats / 256 thr
        const int row = f >> 5;
        const int c   = f & 31;
        const int b   = row * 256 + c;
        f32x4 v0 = *(const f32x4*)&smem[b];
        f32x4 v1 = *(const f32x4*)&smem[b + 64];
        f32x4 v2 = *(const f32x4*)&smem[b + 128];
        f32x4 v3 = *(const f32x4*)&smem[b + 192];
        f32x4 s = (v0 + v1) + (v2 + v3);
        *(f32x4*)(op + f) = s;
    }
}

extern "C" void kernel_launch(void* const* d_in, const int* in_sizes, int n_in,
                              void* d_out, int out_size, void* d_ws, size_t ws_size,
                              hipStream_t stream) {
    const float* x = (const float*)d_in[0];   // [65536, 256] fp32
    const float* w = (const float*)d_in[1];   // [32, 256, 8] fp32
    float* out = (float*)d_out;               // [65536, 32] fp32
    short* wB = (short*)d_ws;                 // 128 KB bf16 packed weights

    prep_w_kernel<<<256, 256, 0, stream>>>(w, wB);
    cheb_mm_kernel<<<2048, 256, 0, stream>>>(x, wB, out);
}